// Round 1
// baseline (1464.244 us; speedup 1.0000x reference)
//
#include <hip/hip_runtime.h>

// Fused windowed-MHSA for MI355X (gfx950).
// fp16 MFMA (16x16x32) for all four GEMMs, fp32 LN/softmax.
// One workgroup per window (t=49 padded to 64 rows), 8 waves.

typedef _Float16 f16;
typedef _Float16 f16x8 __attribute__((ext_vector_type(8)));
typedef float    f32x4 __attribute__((ext_vector_type(4)));

#define MFMA16(a, b, c) __builtin_amdgcn_mfma_f32_16x16x32_f16((a), (b), (c), 0, 0, 0)

// ---- prep: weights fp32 -> fp16 in workspace ----
__global__ void prep_weights(const float* __restrict__ Wqkv, const float* __restrict__ Wout,
                             f16* __restrict__ Wqkv16, f16* __restrict__ Wout16) {
    int i = blockIdx.x * 256 + threadIdx.x;          // 432*256 = 110592 exactly
    if (i < 110592) Wqkv16[i] = (f16)Wqkv[i];
    if (i < 36864)  Wout16[i] = (f16)Wout[i];
}

// ---- prep: relative-position-bias table, padded 6x64x64, matching the
// reference's (2401,6) -> (6,49,49) C-order reshape exactly.
// cols >= 49 get -1e30 (softmax mask for the 49->64 pad). ----
__global__ void prep_rpb(const float* __restrict__ rel_table, const int* __restrict__ rel_idx,
                         float* __restrict__ rpb) {
    int i = blockIdx.x * 256 + threadIdx.x;          // 6*64*64 = 24576
    if (i >= 6 * 64 * 64) return;
    int a = i >> 12, q = (i >> 6) & 63, k = i & 63;
    float v;
    if (q < 49 && k < 49) {
        int f = a * 2401 + q * 49 + k;               // reference reshape: flat = a*2401+q*49+k
        v = rel_table[rel_idx[f / 6] * 6 + (f % 6)];
    } else {
        v = (k >= 49) ? -1e30f : 0.0f;
    }
    rpb[i] = v;
}

__global__ __launch_bounds__(512, 2)
void mhsa_main(const float* __restrict__ X,
               const float* __restrict__ q_gamma, const float* __restrict__ q_beta,
               const float* __restrict__ k_gamma, const float* __restrict__ k_beta,
               const float* __restrict__ b_out,
               const f16* __restrict__ Wqkv16, const f16* __restrict__ Wout16,
               const float* __restrict__ rpb,
               float* __restrict__ out) {
    // Row pitches chosen so row-stride mod 32 dwords == 4 -> 2-way bank alias (free).
    __shared__ __align__(16) f16 Xs[64][200];     // X window, fp16           25600 B
    __shared__ __align__(16) f16 Wh[96][200];     // per-head W slice         38400 B
    __shared__ __align__(16) f16 Qs[64][40];      // LN'd Q                    5120 B
    __shared__ __align__(16) f16 Ks[64][40];      // LN'd K                    5120 B
    __shared__ __align__(16) f16 VsT[32][72];     // V transposed (d, token)   4608 B
    __shared__ __align__(16) f16 Ps[64][72];      // softmax probs             9216 B
    __shared__ __align__(16) f16 Vts[64][200];    // concat head outputs      25600 B
    __shared__ __align__(16) f16 Wouts[192][40];  // W_out k-chunk            15360 B
                                                  // total 129024 B -> 1 block/CU

    const int tid  = threadIdx.x;
    const int wave = tid >> 6, lane = tid & 63;
    const int lrow = lane & 15, lgr = lane >> 4;   // 16-lane group id 0..3
    const int mt   = wave & 3,  ng  = wave >> 2;   // m-tile, n-group
    const int w    = blockIdx.x;
    const size_t xbase = (size_t)w * 49 * 192;

    // LN params (indexed by within-head channel only -> hoist out of head loop)
    float qg0 = q_gamma[lrow], qg1 = q_gamma[16 + lrow];
    float qb0 = q_beta[lrow],  qb1 = q_beta[16 + lrow];
    float kg0 = k_gamma[lrow], kg1 = k_gamma[16 + lrow];
    float kb0 = k_beta[lrow],  kb1 = k_beta[16 + lrow];
    float g0 = ng ? kg0 : qg0, g1 = ng ? kg1 : qg1;
    float e0 = ng ? kb0 : qb0, e1 = ng ? kb1 : qb1;

    // ---- stage X (rows 49..63 zero) ----
    for (int c = tid; c < 64 * 48; c += 512) {
        int row = c / 48, c4 = (c % 48) * 4;
        float4 v = {0.f, 0.f, 0.f, 0.f};
        if (row < 49) v = *(const float4*)&X[xbase + row * 192 + c4];
        Xs[row][c4 + 0] = (f16)v.x;
        Xs[row][c4 + 1] = (f16)v.y;
        Xs[row][c4 + 2] = (f16)v.z;
        Xs[row][c4 + 3] = (f16)v.w;
    }

    for (int h = 0; h < 6; ++h) {
        __syncthreads();                                   // Xs ready / prev readers done
        // ---- stage per-head weight slice: rows 96h..96h+95 of W_qkv ----
        const f16* Wp = Wqkv16 + h * 96 * 192;
        for (int c = tid; c < 96 * 24; c += 512) {
            int r = c / 24, k8 = (c % 24) * 8;
            *(f16x8*)&Wh[r][k8] = *(const f16x8*)&Wp[r * 192 + k8];
        }
        __syncthreads();

        // ---- GEMM1: qkv head tiles. n-tile map: ng0={Q0,Q1,V0} ng1={K0,K1,V1}
        // so each wave owns a complete 32-col LN reduction. ----
        f32x4 acc0 = {0, 0, 0, 0}, acc1 = {0, 0, 0, 0}, acc2 = {0, 0, 0, 0};
        const int cb0 = ng ? 32 : 0;        // Q or K base col
        const int cb2 = 64 + 16 * ng;       // V tile col
        for (int k0 = 0; k0 < 192; k0 += 32) {
            f16x8 a  = *(const f16x8*)&Xs[16 * mt + lrow][k0 + 8 * lgr];
            f16x8 b0 = *(const f16x8*)&Wh[cb0 + lrow][k0 + 8 * lgr];
            f16x8 b1 = *(const f16x8*)&Wh[cb0 + 16 + lrow][k0 + 8 * lgr];
            f16x8 b2 = *(const f16x8*)&Wh[cb2 + lrow][k0 + 8 * lgr];
            acc0 = MFMA16(a, b0, acc0);
            acc1 = MFMA16(a, b1, acc1);
            acc2 = MFMA16(a, b2, acc2);
        }
        // ---- LN over d=32 (Q for ng=0, K for ng=1); V passthrough transposed ----
        for (int r = 0; r < 4; ++r) {
            float v0 = acc0[r], v1 = acc1[r];
            float s = v0 + v1, s2 = v0 * v0 + v1 * v1;
            for (int off = 1; off < 16; off <<= 1) {
                s  += __shfl_xor(s, off);
                s2 += __shfl_xor(s2, off);
            }
            float mu   = s * (1.0f / 32.0f);
            float var  = s2 * (1.0f / 32.0f) - mu * mu;
            float rstd = rsqrtf(var + 1e-5f);
            int row = 16 * mt + 4 * lgr + r;
            f16 y0 = (f16)((v0 - mu) * rstd * g0 + e0);
            f16 y1 = (f16)((v1 - mu) * rstd * g1 + e1);
            if (ng == 0) { Qs[row][lrow] = y0; Qs[row][16 + lrow] = y1; }
            else         { Ks[row][lrow] = y0; Ks[row][16 + lrow] = y1; }
            VsT[16 * ng + lrow][row] = (f16)acc2[r];
        }
        __syncthreads();

        // ---- attention for this head: waves 0..3 (one 16-row q-tile each) ----
        if (wave < 4) {
            f16x8 aq = *(const f16x8*)&Qs[16 * mt + lrow][8 * lgr];
            f32x4 s[4];
            for (int nt = 0; nt < 4; ++nt) {
                f16x8 bk = *(const f16x8*)&Ks[16 * nt + lrow][8 * lgr];
                f32x4 z = {0, 0, 0, 0};
                s[nt] = MFMA16(aq, bk, z);
            }
            const float* rpbh = rpb + h * 4096;
            for (int nt = 0; nt < 4; ++nt)
                for (int r = 0; r < 4; ++r) {
                    int row = 16 * mt + 4 * lgr + r, col = 16 * nt + lrow;
                    s[nt][r] = s[nt][r] * 0.17677669529663687f + rpbh[row * 64 + col];
                }
            float linv[4];
            for (int r = 0; r < 4; ++r) {
                float m = fmaxf(fmaxf(s[0][r], s[1][r]), fmaxf(s[2][r], s[3][r]));
                for (int off = 1; off < 16; off <<= 1) m = fmaxf(m, __shfl_xor(m, off));
                float l = 0.f;
                for (int nt = 0; nt < 4; ++nt) {
                    float p = __expf(s[nt][r] - m);
                    s[nt][r] = p;
                    l += p;
                }
                for (int off = 1; off < 16; off <<= 1) l += __shfl_xor(l, off);
                linv[r] = 1.0f / l;
            }
            for (int nt = 0; nt < 4; ++nt)
                for (int r = 0; r < 4; ++r)
                    Ps[16 * mt + 4 * lgr + r][16 * nt + lrow] = (f16)s[nt][r];
            // same-wave LDS write->read hazard (different lanes): drain ds queue.
            asm volatile("s_waitcnt lgkmcnt(0)" ::: "memory");
            __builtin_amdgcn_sched_barrier(0);

            f32x4 av0 = {0, 0, 0, 0}, av1 = {0, 0, 0, 0};
            for (int k0 = 0; k0 < 64; k0 += 32) {
                f16x8 ap  = *(const f16x8*)&Ps[16 * mt + lrow][k0 + 8 * lgr];
                f16x8 bv0 = *(const f16x8*)&VsT[lrow][k0 + 8 * lgr];
                f16x8 bv1 = *(const f16x8*)&VsT[16 + lrow][k0 + 8 * lgr];
                av0 = MFMA16(ap, bv0, av0);
                av1 = MFMA16(ap, bv1, av1);
            }
            for (int r = 0; r < 4; ++r) {
                int row = 16 * mt + 4 * lgr + r;
                Vts[row][h * 32 + lrow]      = (f16)(av0[r] * linv[r]);
                Vts[row][h * 32 + 16 + lrow] = (f16)(av1[r] * linv[r]);
            }
        }
    }
    __syncthreads();

    // ---- final GEMM: out = Vts @ W_out^T + b_out (M=64, N=192, K=192) ----
    f32x4 o[6];
    for (int nt = 0; nt < 6; ++nt) o[nt] = (f32x4){0, 0, 0, 0};
    for (int k0 = 0; k0 < 192; k0 += 32) {
        __syncthreads();                               // Wouts readers of prev chunk done
        for (int c = tid; c < 192 * 4; c += 512) {
            int n = c / 4, k8 = (c % 4) * 8;
            *(f16x8*)&Wouts[n][k8] = *(const f16x8*)&Wout16[n * 192 + k0 + k8];
        }
        __syncthreads();
        f16x8 a = *(const f16x8*)&Vts[16 * mt + lrow][k0 + 8 * lgr];
        for (int nt = 0; nt < 6; ++nt) {
            f16x8 b = *(const f16x8*)&Wouts[96 * ng + 16 * nt + lrow][8 * lgr];
            o[nt] = MFMA16(a, b, o[nt]);
        }
    }
    for (int nt = 0; nt < 6; ++nt) {
        int col = 96 * ng + 16 * nt + lrow;
        float bo = b_out[col];
        for (int r = 0; r < 4; ++r) {
            int row = 16 * mt + 4 * lgr + r;
            if (row < 49) out[xbase + row * 192 + col] = o[nt][r] + bo;
        }
    }
}

extern "C" void kernel_launch(void* const* d_in, const int* in_sizes, int n_in,
                              void* d_out, int out_size, void* d_ws, size_t ws_size,
                              hipStream_t stream) {
    const float* X         = (const float*)d_in[0];
    const float* Wqkv      = (const float*)d_in[1];
    const float* qg        = (const float*)d_in[2];
    const float* qb        = (const float*)d_in[3];
    const float* kg        = (const float*)d_in[4];
    const float* kb        = (const float*)d_in[5];
    const float* rel_table = (const float*)d_in[6];
    const int*   rel_idx   = (const int*)d_in[7];
    const float* Wout      = (const float*)d_in[8];
    const float* bo        = (const float*)d_in[9];
    float* out = (float*)d_out;

    // workspace layout: Wqkv16 [110592 f16] | Wout16 [36864 f16] | rpb [24576 f32]
    f16*   Wqkv16 = (f16*)d_ws;
    f16*   Wout16 = Wqkv16 + 110592;
    float* rpb    = (float*)((char*)d_ws + 294912);

    prep_weights<<<432, 256, 0, stream>>>(Wqkv, Wout, Wqkv16, Wout16);
    prep_rpb<<<96, 256, 0, stream>>>(rel_table, rel_idx, rpb);
    mhsa_main<<<8192, 512, 0, stream>>>(X, qg, qb, kg, kb, bo, Wqkv16, Wout16, rpb, out);
}